// Round 1
// baseline (185.664 us; speedup 1.0000x reference)
//
#include <hip/hip_runtime.h>
#include <hip/hip_bf16.h>

#define N_ROWS 8192
#define DIM 128

constexpr float INV_T  = 2.5f;                  // 1 / 0.4
constexpr float E_REFL = 12.182493960703473f;   // exp(2.5) = diagonal of refl

typedef short short8 __attribute__((ext_vector_type(8)));
typedef float f32x4  __attribute__((ext_vector_type(4)));

typedef const __attribute__((address_space(1))) unsigned int* gas_u32;
typedef __attribute__((address_space(3))) unsigned int*       las_u32;

__device__ __forceinline__ unsigned short f2bf(float f) {
    __hip_bfloat16 h = __float2bfloat16(f);
    return *reinterpret_cast<unsigned short*>(&h);
}

// ---------------------------------------------------------------------------
// Kernel 1: L2-normalize rows of out/aug_out (fp32), store bf16 copies,
// compute per-row cross dot (fp32), zero the 4 sum arrays.
// One wave per row; 2048 blocks x 256 threads.
// ---------------------------------------------------------------------------
__global__ __launch_bounds__(256) void norm_kernel(
    const float* __restrict__ outp, const float* __restrict__ augp,
    unsigned short* __restrict__ z1, unsigned short* __restrict__ z2,
    float* __restrict__ posdot, float* __restrict__ sums)
{
    int gt = blockIdx.x * 256 + threadIdx.x;
    if (gt < 4 * N_ROWS) sums[gt] = 0.0f;

    const int w    = threadIdx.x >> 6;
    const int lane = threadIdx.x & 63;
    const int row  = blockIdx.x * 4 + w;

    float2 a = *(const float2*)(outp + row * DIM + lane * 2);
    float2 b = *(const float2*)(augp + row * DIM + lane * 2);

    float ssa = a.x * a.x + a.y * a.y;
    float ssb = b.x * b.x + b.y * b.y;
    #pragma unroll
    for (int m = 1; m < 64; m <<= 1) {
        ssa += __shfl_xor(ssa, m);
        ssb += __shfl_xor(ssb, m);
    }
    float inva = 1.0f / fmaxf(sqrtf(ssa), 1e-12f);
    float invb = 1.0f / fmaxf(sqrtf(ssb), 1e-12f);

    float xa0 = a.x * inva, xa1 = a.y * inva;
    float xb0 = b.x * invb, xb1 = b.y * invb;

    ushort2 s1; s1.x = f2bf(xa0); s1.y = f2bf(xa1);
    ushort2 s2; s2.x = f2bf(xb0); s2.y = f2bf(xb1);
    *(ushort2*)(z1 + row * DIM + lane * 2) = s1;
    *(ushort2*)(z2 + row * DIM + lane * 2) = s2;

    float d = xa0 * xb0 + xa1 * xb1;
    #pragma unroll
    for (int m = 1; m < 64; m <<= 1) d += __shfl_xor(d, m);
    if (lane == 0) posdot[row] = d;
}

// ---------------------------------------------------------------------------
// Kernel 2: fused Gram row/col-sum.  C = exp((X Y^T)/tau); atomically
// accumulate rowsum[i] += sum_j C[i][j] and (doCol) colsum[j] += sum_i C[i][j].
// Block = 256 thr (4 waves); tile = 128x128, K = 128 (single pass).
// LDS staged via global_load_lds(16B) with XOR-pre-swizzled global source so
// that swizzled ds_read_b128 fragment loads are bank-conflict-free.
// ---------------------------------------------------------------------------
__global__ __launch_bounds__(256) void gram_kernel(
    const unsigned short* __restrict__ X, const unsigned short* __restrict__ Y,
    float* __restrict__ rowsum, float* __restrict__ colsum, int doCol)
{
    __shared__ char Xs[128 * 256];   // 32 KB, row-major [128 rows][256 B]
    __shared__ char Ys[128 * 256];   // 32 KB

    const int tid  = threadIdx.x;
    const int w    = tid >> 6;
    const int lane = tid & 63;
    const int bi   = blockIdx.y;
    const int bj   = blockIdx.x;

    const char* gx = (const char*)X + (size_t)bi * (128 * 256);
    const char* gy = (const char*)Y + (size_t)bj * (128 * 256);

    // stage: LDS[linear off] = G[swz(off)]  (swz is an involution on bits 4..6)
    #pragma unroll
    for (int it = 0; it < 8; ++it) {
        int off = w * 8192 + it * 1024 + lane * 16;
        int swz = off ^ (((off >> 8) & 7) << 4);
        __builtin_amdgcn_global_load_lds((gas_u32)(gx + swz),
                                         (las_u32)(Xs + w * 8192 + it * 1024), 16, 0, 0);
        __builtin_amdgcn_global_load_lds((gas_u32)(gy + swz),
                                         (las_u32)(Ys + w * 8192 + it * 1024), 16, 0, 0);
    }
    __syncthreads();

    const int l16 = lane & 15;
    const int lg  = lane >> 4;   // 0..3

    f32x4 acc[2][8];
    #pragma unroll
    for (int rt = 0; rt < 2; ++rt)
        #pragma unroll
        for (int ct = 0; ct < 8; ++ct)
            acc[rt][ct] = (f32x4){0.f, 0.f, 0.f, 0.f};

    #pragma unroll
    for (int ks = 0; ks < 4; ++ks) {
        const int kb = ks * 64 + lg * 16;     // byte offset of this lane's k-chunk
        short8 afrag[2], bfrag[8];
        #pragma unroll
        for (int rt = 0; rt < 2; ++rt) {
            int r   = w * 32 + rt * 16 + l16;
            int off = r * 256 + kb;
            afrag[rt] = *(const short8*)(Xs + (off ^ ((r & 7) << 4)));
        }
        #pragma unroll
        for (int ct = 0; ct < 8; ++ct) {
            int r   = ct * 16 + l16;
            int off = r * 256 + kb;
            bfrag[ct] = *(const short8*)(Ys + (off ^ ((r & 7) << 4)));
        }
        #pragma unroll
        for (int rt = 0; rt < 2; ++rt)
            #pragma unroll
            for (int ct = 0; ct < 8; ++ct)
                acc[rt][ct] = __builtin_amdgcn_mfma_f32_16x16x32_bf16(
                    afrag[rt], bfrag[ct], acc[rt][ct], 0, 0, 0);
    }

    // epilogue: e = exp(dot/tau); accumulate row sums and col sums
    float rsum[2][4] = {{0.f,0.f,0.f,0.f},{0.f,0.f,0.f,0.f}};
    float csum[8]    = {0.f,0.f,0.f,0.f,0.f,0.f,0.f,0.f};
    #pragma unroll
    for (int rt = 0; rt < 2; ++rt)
        #pragma unroll
        for (int ct = 0; ct < 8; ++ct) {
            f32x4 v = acc[rt][ct];
            #pragma unroll
            for (int r = 0; r < 4; ++r) {
                float e = __expf(v[r] * INV_T);
                rsum[rt][r] += e;
                csum[ct]    += e;
            }
        }

    // row sums: C/D col = lane&15 -> reduce across the 16 lanes of the group
    #pragma unroll
    for (int rt = 0; rt < 2; ++rt)
        #pragma unroll
        for (int r = 0; r < 4; ++r) {
            float v = rsum[rt][r];
            v += __shfl_xor(v, 1);  v += __shfl_xor(v, 2);
            v += __shfl_xor(v, 4);  v += __shfl_xor(v, 8);
            if (l16 == 0)
                atomicAdd(&rowsum[bi * 128 + w * 32 + rt * 16 + lg * 4 + r], v);
        }

    // col sums: reduce across the 4 row-groups (lane bits 4,5)
    if (doCol) {
        #pragma unroll
        for (int ct = 0; ct < 8; ++ct) {
            float v = csum[ct];
            v += __shfl_xor(v, 16); v += __shfl_xor(v, 32);
            if (lg == 0)
                atomicAdd(&colsum[bj * 128 + ct * 16 + l16], v);
        }
    }
}

// ---------------------------------------------------------------------------
// Kernel 3: final reduction over rows -> scalar mean loss.
// sums layout: [S1 | S2 | Rb | Cb], each N_ROWS floats.
// ---------------------------------------------------------------------------
__global__ __launch_bounds__(256) void final_kernel(
    const float* __restrict__ sums, const float* __restrict__ posdot,
    float* __restrict__ outv)
{
    float local = 0.0f;
    for (int i = threadIdx.x; i < N_ROWS; i += 256) {
        float d1 = sums[i]          + sums[2 * N_ROWS + i] - E_REFL;
        float d2 = sums[N_ROWS + i] + sums[3 * N_ROWS + i] - E_REFL;
        local += -posdot[i] * INV_T + 0.5f * (logf(d1) + logf(d2));
    }
    __shared__ float red[256];
    red[threadIdx.x] = local;
    __syncthreads();
    for (int s = 128; s > 0; s >>= 1) {
        if ((int)threadIdx.x < s) red[threadIdx.x] += red[threadIdx.x + s];
        __syncthreads();
    }
    if (threadIdx.x == 0) outv[0] = red[0] * (1.0f / N_ROWS);
}

// ---------------------------------------------------------------------------
extern "C" void kernel_launch(void* const* d_in, const int* in_sizes, int n_in,
                              void* d_out, int out_size, void* d_ws, size_t ws_size,
                              hipStream_t stream) {
    const float* outp = (const float*)d_in[0];
    const float* augp = (const float*)d_in[1];

    char* ws = (char*)d_ws;
    unsigned short* z1 = (unsigned short*)ws;                         // 2 MB bf16
    unsigned short* z2 = (unsigned short*)(ws + 2097152);             // 2 MB bf16
    float* sums   = (float*)(ws + 4194304);                           // 4*8192 f32
    float* posdot = (float*)(ws + 4194304 + 131072);                  // 8192 f32
    float* outf   = (float*)d_out;

    hipLaunchKernelGGL(norm_kernel, dim3(2048), dim3(256), 0, stream,
                       outp, augp, z1, z2, posdot, sums);

    dim3 g(64, 64);
    hipLaunchKernelGGL(gram_kernel, g, dim3(256), 0, stream,
                       z1, z1, sums,              (float*)nullptr, 0);
    hipLaunchKernelGGL(gram_kernel, g, dim3(256), 0, stream,
                       z2, z2, sums + N_ROWS,     (float*)nullptr, 0);
    hipLaunchKernelGGL(gram_kernel, g, dim3(256), 0, stream,
                       z1, z2, sums + 2 * N_ROWS, sums + 3 * N_ROWS, 1);

    hipLaunchKernelGGL(final_kernel, dim3(1), dim3(256), 0, stream,
                       sums, posdot, outf);
}

// Round 2
// 91.094 us; speedup vs baseline: 2.0382x; 2.0382x over previous
//
#include <hip/hip_runtime.h>
#include <hip/hip_bf16.h>

#define NR  8192      // rows per view
#define M   16384     // 2*NR concatenated
#define DIM 128
#define ROWB 256      // bytes per bf16 row
#define TILEB 32768   // 128 rows * 256 B

constexpr float INV_T   = 2.5f;                  // 1/0.4
constexpr float SCALE_S = 1.89914134f;           // sqrt(2.5 * log2(e)); s^2 = 3.6067376
constexpr float E_REFL  = 12.182493960703473f;   // exp(2.5)

typedef short short8 __attribute__((ext_vector_type(8)));
typedef float f32x4  __attribute__((ext_vector_type(4)));

typedef const __attribute__((address_space(1))) unsigned int* gas_u32;
typedef __attribute__((address_space(3))) unsigned int*       las_u32;

__device__ __forceinline__ unsigned short f2bf(float f) {
    __hip_bfloat16 h = __float2bfloat16(f);
    return *reinterpret_cast<unsigned short*>(&h);
}

__device__ __forceinline__ float fexp2(float x) {
#if __has_builtin(__builtin_amdgcn_exp2f)
    return __builtin_amdgcn_exp2f(x);
#else
    return exp2f(x);
#endif
}

// Stage one 128x128 bf16 tile (32 KB) global->LDS, 8 x global_load_lds(16B)
// per wave. LDS dest is linear; global src is XOR-pre-swizzled (involution on
// byte bits 4..6 keyed by row&7) so swizzled ds_read_b128 is low-conflict.
__device__ __forceinline__ void stage_tile(const char* __restrict__ gsrc,
                                           char* lds, int w, int lane) {
    #pragma unroll
    for (int it = 0; it < 8; ++it) {
        int off = w * 8192 + it * 1024 + lane * 16;
        int swz = off ^ (((off >> 8) & 7) << 4);
        __builtin_amdgcn_global_load_lds((gas_u32)(gsrc + swz),
                                         (las_u32)(lds + w * 8192 + it * 1024),
                                         16, 0, 0);
    }
}

// ---------------------------------------------------------------------------
// Kernel 1: L2-normalize rows; store bf16 Z = [z1n; z2n] PRE-SCALED by
// SCALE_S (so MFMA output is directly the exp2 argument); fp32 cross dot;
// zero the rowsum array R.
// ---------------------------------------------------------------------------
__global__ __launch_bounds__(256) void norm_kernel(
    const float* __restrict__ outp, const float* __restrict__ augp,
    unsigned short* __restrict__ Z, float* __restrict__ R,
    float* __restrict__ posdot)
{
    int gt = blockIdx.x * 256 + threadIdx.x;
    if (gt < M) R[gt] = 0.0f;

    const int w    = threadIdx.x >> 6;
    const int lane = threadIdx.x & 63;
    const int row  = blockIdx.x * 4 + w;

    float2 a = *(const float2*)(outp + row * DIM + lane * 2);
    float2 b = *(const float2*)(augp + row * DIM + lane * 2);

    float ssa = a.x * a.x + a.y * a.y;
    float ssb = b.x * b.x + b.y * b.y;
    #pragma unroll
    for (int m = 1; m < 64; m <<= 1) {
        ssa += __shfl_xor(ssa, m);
        ssb += __shfl_xor(ssb, m);
    }
    float inva = 1.0f / fmaxf(sqrtf(ssa), 1e-12f);
    float invb = 1.0f / fmaxf(sqrtf(ssb), 1e-12f);

    float xa0 = a.x * inva, xa1 = a.y * inva;   // unit-normalized (fp32)
    float xb0 = b.x * invb, xb1 = b.y * invb;

    ushort2 s1; s1.x = f2bf(xa0 * SCALE_S); s1.y = f2bf(xa1 * SCALE_S);
    ushort2 s2; s2.x = f2bf(xb0 * SCALE_S); s2.y = f2bf(xb1 * SCALE_S);
    *(ushort2*)(Z + (size_t)row * DIM + lane * 2)        = s1;
    *(ushort2*)(Z + (size_t)(NR + row) * DIM + lane * 2) = s2;

    float d = xa0 * xb0 + xa1 * xb1;
    #pragma unroll
    for (int m = 1; m < 64; m <<= 1) d += __shfl_xor(d, m);
    if (lane == 0) posdot[row] = d;
}

// ---------------------------------------------------------------------------
// Kernel 2: row sums of exp2(Zs * Zs^T)  (Zs pre-scaled so dot = exp2 arg).
// Grid (4 chunks, 128 row-tiles) = 512 blocks = 2/CU.  Block: 256 thr.
// X-tile staged once -> A-frags live in registers for all 32 Y-iterations.
// Y-tiles double-buffered (2-phase: issue stage(t+1) before compute(t)).
// Row sums accumulate in registers; single shuffle-reduce + atomic at end.
// ---------------------------------------------------------------------------
__global__ __launch_bounds__(256, 2) void gram_kernel(
    const unsigned short* __restrict__ Z, float* __restrict__ R)
{
    __shared__ char buf[2][TILEB];   // 64 KB total -> 2 blocks/CU

    const int tid   = threadIdx.x;
    const int w     = tid >> 6;
    const int lane  = tid & 63;
    const int chunk = blockIdx.x;    // 0..3  (32 col-tiles each)
    const int bi    = blockIdx.y;    // 0..127 row tile

    const char* Zb = (const char*)Z;

    // prologue: stage X-tile and Y-tile(0)
    stage_tile(Zb + (size_t)bi * TILEB,           buf[0], w, lane);
    stage_tile(Zb + (size_t)(chunk * 32) * TILEB, buf[1], w, lane);
    __syncthreads();

    const int l16 = lane & 15;
    const int lg  = lane >> 4;

    // A-fragments -> registers (rows w*32 .. w*32+31 of the tile)
    short8 afrag[2][4];
    #pragma unroll
    for (int rt = 0; rt < 2; ++rt)
        #pragma unroll
        for (int ks = 0; ks < 4; ++ks) {
            int r   = w * 32 + rt * 16 + l16;
            int off = r * 256 + ks * 64 + lg * 16;
            afrag[rt][ks] = *(const short8*)(buf[0] + (off ^ ((r & 7) << 4)));
        }
    __syncthreads();   // all waves done reading X before t=1 overwrites buf[0]

    float rs[2][4] = {{0.f,0.f,0.f,0.f},{0.f,0.f,0.f,0.f}};
    const f32x4 zero4 = (f32x4){0.f, 0.f, 0.f, 0.f};

    for (int t = 0; t < 32; ++t) {
        char* cur = buf[1 ^ (t & 1)];
        char* nxt = buf[t & 1];
        if (t + 1 < 32)
            stage_tile(Zb + (size_t)(chunk * 32 + t + 1) * TILEB, nxt, w, lane);

        f32x4 acc[2][8];
        #pragma unroll
        for (int ks = 0; ks < 4; ++ks) {
            short8 bfrag[8];
            #pragma unroll
            for (int ct = 0; ct < 8; ++ct) {
                int r   = ct * 16 + l16;
                int off = r * 256 + ks * 64 + lg * 16;
                bfrag[ct] = *(const short8*)(cur + (off ^ ((r & 7) << 4)));
            }
            #pragma unroll
            for (int rt = 0; rt < 2; ++rt)
                #pragma unroll
                for (int ct = 0; ct < 8; ++ct)
                    acc[rt][ct] = (ks == 0)
                        ? __builtin_amdgcn_mfma_f32_16x16x32_bf16(
                              afrag[rt][0], bfrag[ct], zero4, 0, 0, 0)
                        : __builtin_amdgcn_mfma_f32_16x16x32_bf16(
                              afrag[rt][ks], bfrag[ct], acc[rt][ct], 0, 0, 0);
        }

        // epilogue: rowsum += exp2(acc)   (arg already scaled)
        #pragma unroll
        for (int rt = 0; rt < 2; ++rt)
            #pragma unroll
            for (int ct = 0; ct < 8; ++ct) {
                f32x4 v = acc[rt][ct];
                #pragma unroll
                for (int r = 0; r < 4; ++r)
                    rs[rt][r] += fexp2(v[r]);
            }

        __syncthreads();   // stage(t+1) complete + all waves done with cur
    }

    // reduce row sums across the 16 lanes holding one row's columns
    #pragma unroll
    for (int rt = 0; rt < 2; ++rt)
        #pragma unroll
        for (int r = 0; r < 4; ++r) {
            float v = rs[rt][r];
            v += __shfl_xor(v, 1);  v += __shfl_xor(v, 2);
            v += __shfl_xor(v, 4);  v += __shfl_xor(v, 8);
            if (l16 == 0)
                atomicAdd(&R[bi * 128 + w * 32 + rt * 16 + lg * 4 + r], v);
        }
}

// ---------------------------------------------------------------------------
// Kernel 3: loss = mean_i [ -dot_i/tau + 0.5(log(R_i - E) + log(R_{NR+i} - E)) ]
// ---------------------------------------------------------------------------
__global__ __launch_bounds__(256) void final_kernel(
    const float* __restrict__ R, const float* __restrict__ posdot,
    float* __restrict__ outv)
{
    float local = 0.0f;
    for (int i = threadIdx.x; i < NR; i += 256) {
        float d1 = R[i]      - E_REFL;
        float d2 = R[NR + i] - E_REFL;
        local += -posdot[i] * INV_T + 0.5f * (logf(d1) + logf(d2));
    }
    __shared__ float red[256];
    red[threadIdx.x] = local;
    __syncthreads();
    for (int s = 128; s > 0; s >>= 1) {
        if ((int)threadIdx.x < s) red[threadIdx.x] += red[threadIdx.x + s];
        __syncthreads();
    }
    if (threadIdx.x == 0) outv[0] = red[0] * (1.0f / NR);
}

// ---------------------------------------------------------------------------
extern "C" void kernel_launch(void* const* d_in, const int* in_sizes, int n_in,
                              void* d_out, int out_size, void* d_ws, size_t ws_size,
                              hipStream_t stream) {
    const float* outp = (const float*)d_in[0];
    const float* augp = (const float*)d_in[1];

    char* ws = (char*)d_ws;
    unsigned short* Z = (unsigned short*)ws;                  // 4 MB bf16 [16384][128]
    float* R      = (float*)(ws + 4194304);                   // 16384 f32 row sums
    float* posdot = (float*)(ws + 4194304 + 65536);           // 8192 f32
    float* outf   = (float*)d_out;

    hipLaunchKernelGGL(norm_kernel, dim3(2048), dim3(256), 0, stream,
                       outp, augp, Z, R, posdot);

    hipLaunchKernelGGL(gram_kernel, dim3(4, 128), dim3(256), 0, stream,
                       Z, R);

    hipLaunchKernelGGL(final_kernel, dim3(1), dim3(256), 0, stream,
                       R, posdot, outf);
}